// Round 14
// baseline (212.703 us; speedup 1.0000x reference)
//
#include <hip/hip_runtime.h>
#include <stdint.h>

#define KSTEPS 20
#define EPB 4          // batch elements per block
#define NBLOCKS 1024   // 4096 / EPB
#define NTHREADS 512

// ---- LDS layout (bytes) ----
// wq : bf16, NEGATED, FRAGMENT-LINEAR with PADDED fb stride:
//      byte(e, fb, slot, h) = e*33792 + fb*1056 + slot*16 + h*8
//      slot = kg_s*16 + r15 (== lane id on the read side), fb = mtile*4 + kt.
//      Reads: base + l*16 + fb*1056 (imm) -> conflict-free, 16B-aligned.
//      Writes: +32B pad per fb -> 16 distinct 8B positions per wave-write.
// hcatB : bf16 [4][272] (cols 0..127 = -grad, 128..255 = x)
// h0B/h1B : bf16 [4][272]
#define WQ_E_STRIDE 33792
#define FB_STRIDE   1056
#define WQ_OFF      0          // 4*33792 = 135168
#define HB_OFF      135168
#define H0B_OFF     137344
#define H1B_OFF     139520
#define SMEM_BYTES  141696

#define ACT_STRIDE 544   // bytes per batch row of bf16 activation buffers

typedef short bf16x8 __attribute__((ext_vector_type(8)));
typedef float f32x4  __attribute__((ext_vector_type(4)));

static __device__ __forceinline__ uint32_t f2bf(float x) {  // RNE round to bf16 (as u16)
    union { float f; uint32_t u; } v; v.f = x;
    return (v.u + 0x7fffu + ((v.u >> 16) & 1u)) >> 16;
}
// v_cvt_pk_bf16_f32: {lo=bf16(a), hi=bf16(b)}, RNE, 1 VALU op per 2 values.
static __device__ __forceinline__ uint32_t packbf2(float a, float b) {
    uint32_t r;
    asm("v_cvt_pk_bf16_f32 %0, %1, %2" : "=v"(r) : "v"(a), "v"(b));
    return r;
}

// Pack shared MLP weights fp32 -> bf16 in layout [c][r][m] : Wp[(c*R + r)*8 + m] = W[r][8c+m]
// == the mfma_f32_16x16x32_bf16 A-fragment layout (lane = row l&15, k-group l>>4).
__global__ void prep_kernel(const float* __restrict__ W0, const float* __restrict__ W1,
                            const float* __restrict__ V, uint16_t* __restrict__ out)
{
    int i = blockIdx.x * 256 + threadIdx.x;   // 640 blocks * 256 = 163840
    float v;
    if (i < 65536) {
        int c = i >> 11, rest = i & 2047, r = rest >> 3, m = rest & 7;
        v = W0[r * 256 + c * 8 + m];
    } else if (i < 131072) {
        int j = i - 65536;
        int c = j >> 11, rest = j & 2047, r = rest >> 3, m = rest & 7;
        v = W1[r * 256 + c * 8 + m];
    } else {
        int j = i - 131072;
        int c = j >> 10, rest = j & 1023, r = rest >> 3, m = rest & 7;
        v = V[r * 256 + c * 8 + m];
    }
    out[i] = (uint16_t)f2bf(v);
}

// Round-13 post-mortem: 179.2us (+2.4%, predicted 10% -- DS model over-credited;
// phase chain is latency/overlap-bound). Register file confirmed FULL (R9 spill
// at +64, R13 fits at +32). Last untried lever: h0's K splits as [grad | x] and
// the x half (kk=4..7) is valid at STEP START (prev V phase wrote it pre-B4;
// grad writes touch only cols 0..127, disjoint). So half of H0 (8 MFMA + 4 DS
// reads) runs concurrently with the grad phase before B1 into persistent
// partials px0/px1; after B1 only the grad-half remains. Summation order is
// bit-identical to the old 2x4-deep split (acc + accb == acc + px).
__global__
__attribute__((amdgpu_flat_work_group_size(512, 512), amdgpu_waves_per_eu(2, 2)))
void mlprnn_main(
    const float* __restrict__ w, const float* __restrict__ b,
    const uint16_t* __restrict__ wp, float* __restrict__ out)
{
    extern __shared__ char smem[];

    const int t  = threadIdx.x;
    const int e0 = blockIdx.x * EPB;

    // ---- MFMA lane roles ----
    const int l = t & 63, wv = t >> 6;               // wave 0..7
    const int row15 = l & 15;                        // A row within tile / C col
    const int kg    = l >> 4;                        // k-group / C row-group
    const int cm    = l & 3;                         // MLP B source batch
    const bool cok  = row15 < 4;                     // MLP epilogue lanes
    const int mt0 = 2 * wv, mt1 = 2 * wv + 1;        // h0/h1 M-tiles; V tile = wv

    // ---- grad-phase roles: wave -> (element, M-half) ----
    const int e_g  = wv >> 1;                        // element 0..3
    const int mh   = wv & 1;                         // M-half (64 rows)

    const bf16x8* w0v = (const bf16x8*)wp;           // [32][256]
    const bf16x8* w1v = w0v + 32 * 256;
    const bf16x8* vv  = w1v + 32 * 256;              // [32][128]

    // ---- hoist loop-invariant MLP A-fragments into registers ----
    bf16x8 a0w[8], a1w[8], b0w[8], b1w[8], vw[8];
    #pragma unroll
    for (int kk = 0; kk < 8; ++kk) {
        a0w[kk] = w0v[(kk * 4 + kg) * 256 + mt0 * 16 + row15];
        a1w[kk] = w0v[(kk * 4 + kg) * 256 + mt1 * 16 + row15];
        b0w[kk] = w1v[(kk * 4 + kg) * 256 + mt0 * 16 + row15];
        b1w[kk] = w1v[(kk * 4 + kg) * 256 + mt1 * 16 + row15];
        vw[kk]  = vv[(kk * 4 + kg) * 128 + wv * 16 + row15];
    }
    // ---- hoist b for the grad phase: acc seed = b rows (mh*64 + mt*16 + kg*4 ..+4)
    f32x4 bseed[4];
    #pragma unroll
    for (int mt = 0; mt < 4; ++mt)
        bseed[mt] = *(const f32x4*)(b + (size_t)(e0 + e_g) * 128 + mh * 64 + mt * 16 + kg * 4);

    // ---- step 0 shortcut: x=0 -> -grad = b (bit-identical to old k=0 path) ----
    {
        int e = t >> 7, feat = t & 127;
        float bv = b[(size_t)(e0 + e) * 128 + feat];
        *(uint16_t*)(smem + HB_OFF + e * ACT_STRIDE + feat * 2) = (uint16_t)f2bf(bv);
        *(uint16_t*)(smem + HB_OFF + e * ACT_STRIDE + 256 + feat * 2) = 0;  // x = 0
    }
    __syncthreads();

    // ---- staging chunk: 8 iterations of {coalesced f32x4 load, negate+pack, ds_write}
    #define STAGE_CHUNK(C) do {                                                   \
        const float4* wg_ = (const float4*)w;                                     \
        _Pragma("unroll")                                                         \
        for (int it = (C) * 8; it < (C) * 8 + 8; ++it) {                          \
            int g  = it * NTHREADS + t;                                           \
            int e  = g >> 12;                                                     \
            int gg = g & 4095;                                                    \
            int r  = gg >> 5, q = gg & 31;                                        \
            float4 f = wg_[(size_t)(e0 + e) * 4096 + gg];                         \
            uint2 pk = { packbf2(-f.x, -f.y), packbf2(-f.z, -f.w) };              \
            int kt_s = q >> 3, kg_s = (q >> 1) & 3, h = q & 1;                    \
            int fb   = (r >> 4) * 4 + kt_s;                                       \
            int byte = e * WQ_E_STRIDE + fb * FB_STRIDE                           \
                     + (kg_s * 16 + (r & 15)) * 16 + h * 8;                       \
            *(uint2*)(smem + WQ_OFF + byte) = pk;                                 \
        }                                                                         \
    } while (0)

    // grad-phase LDS bases: fragment-linear -> base + l*16 + compile-time fb offset
    const char* wqA = smem + WQ_OFF + e_g * WQ_E_STRIDE + l * 16;
    const char* xB  = smem + HB_OFF + e_g * ACT_STRIDE + 256 + kg * 16;

    // MLP-phase LDS bases
    const char* hbB = smem + HB_OFF  + cm * ACT_STRIDE + kg * 16;
    const char* h0B = smem + H0B_OFF + cm * ACT_STRIDE + kg * 16;
    const char* h1B = smem + H1B_OFF + cm * ACT_STRIDE + kg * 16;

    // gw0h/gw1h (tiles mt 0,1) hoisted after staging completes; declared here.
    bf16x8 gw0h[4], gw1h[4];

    // full-width MLP phase (used for h1, and for step-0 h0)
    #define PHASE_MLP(SRC, AW0, AW1, DST) do {                                    \
        f32x4 acc0 = {0.f, 0.f, 0.f, 0.f}, acc0b = {0.f, 0.f, 0.f, 0.f};          \
        f32x4 acc1 = {0.f, 0.f, 0.f, 0.f}, acc1b = {0.f, 0.f, 0.f, 0.f};          \
        _Pragma("unroll")                                                         \
        for (int kk = 0; kk < 4; ++kk) {                                          \
            bf16x8 bf = *(const bf16x8*)((SRC) + kk * 64);                        \
            acc0 = __builtin_amdgcn_mfma_f32_16x16x32_bf16(AW0[kk], bf, acc0, 0, 0, 0); \
            acc1 = __builtin_amdgcn_mfma_f32_16x16x32_bf16(AW1[kk], bf, acc1, 0, 0, 0); \
        }                                                                         \
        _Pragma("unroll")                                                         \
        for (int kk = 4; kk < 8; ++kk) {                                          \
            bf16x8 bf = *(const bf16x8*)((SRC) + kk * 64);                        \
            acc0b = __builtin_amdgcn_mfma_f32_16x16x32_bf16(AW0[kk], bf, acc0b, 0, 0, 0); \
            acc1b = __builtin_amdgcn_mfma_f32_16x16x32_bf16(AW1[kk], bf, acc1b, 0, 0, 0); \
        }                                                                         \
        acc0 += acc0b; acc1 += acc1b;                                             \
        if (cok) {                                                                \
            uint2 q0 = { packbf2(fmaxf(acc0[0], 0.f), fmaxf(acc0[1], 0.f)),       \
                         packbf2(fmaxf(acc0[2], 0.f), fmaxf(acc0[3], 0.f)) };     \
            uint2 q1 = { packbf2(fmaxf(acc1[0], 0.f), fmaxf(acc1[1], 0.f)),       \
                         packbf2(fmaxf(acc1[2], 0.f), fmaxf(acc1[3], 0.f)) };     \
            *(uint2*)(smem + (DST) + row15 * ACT_STRIDE + (mt0 * 16 + kg * 4) * 2) = q0; \
            *(uint2*)(smem + (DST) + row15 * ACT_STRIDE + (mt1 * 16 + kg * 4) * 2) = q1; \
        }                                                                         \
    } while (0)

    #define PHASE_V(K) do {                                                       \
        f32x4 acc = {0.f, 0.f, 0.f, 0.f}, accb = {0.f, 0.f, 0.f, 0.f};            \
        _Pragma("unroll")                                                         \
        for (int kk = 0; kk < 4; ++kk) {                                          \
            bf16x8 bf = *(const bf16x8*)(h1B + kk * 64);                          \
            acc = __builtin_amdgcn_mfma_f32_16x16x32_bf16(vw[kk], bf, acc, 0, 0, 0); \
        }                                                                         \
        _Pragma("unroll")                                                         \
        for (int kk = 4; kk < 8; ++kk) {                                          \
            bf16x8 bf = *(const bf16x8*)(h1B + kk * 64);                          \
            accb = __builtin_amdgcn_mfma_f32_16x16x32_bf16(vw[kk], bf, accb, 0, 0, 0); \
        }                                                                         \
        acc += accb;                                                              \
        if (cok) {                                                                \
            const int r = wv * 16 + kg * 4;                                       \
            uint2 q = { packbf2(acc[0], acc[1]), packbf2(acc[2], acc[3]) };       \
            *(uint2*)(smem + HB_OFF + row15 * ACT_STRIDE + 256 + r * 2) = q;      \
            if ((K) == KSTEPS - 1) {                                              \
                *(f32x4*)(&out[(size_t)(e0 + row15) * 128 + r]) = acc;            \
            }                                                                     \
        }                                                                         \
    } while (0)

    // ---- step 0 (no grad phase) interleaved with w staging ----
    STAGE_CHUNK(0);
    PHASE_MLP(hbB, a0w, a1w, H0B_OFF); __syncthreads();
    STAGE_CHUNK(1);
    PHASE_MLP(h0B, b0w, b1w, H1B_OFF); __syncthreads();
    STAGE_CHUNK(2);
    PHASE_V(0); __syncthreads();
    STAGE_CHUNK(3);
    __syncthreads();   // wq complete before k=1 grad

    // ---- hoist half the grad A-fragments (tiles mt 0,1; loop-invariant) ----
    #pragma unroll
    for (int kt = 0; kt < 4; ++kt) {
        gw0h[kt] = *(const bf16x8*)(wqA + (((mh * 4 + 0) * 4 + kt) * FB_STRIDE));
        gw1h[kt] = *(const bf16x8*)(wqA + (((mh * 4 + 1) * 4 + kt) * FB_STRIDE));
    }

    // ---- steps 1..19 ----
    #pragma unroll 1
    for (int k = 1; k < KSTEPS; ++k) {
        // ===== phase A: grad MFMAs + h0 x-part MFMAs (overlapped, pre-B1) =====
        // h0's x half (kk=4..7) reads hcat cols 128..255, valid since prev B4;
        // grad writes go to cols 0..127 -- disjoint bytes, no race.
        f32x4 px0 = {0.f, 0.f, 0.f, 0.f};   // h0 x-part partial, tile mt0
        f32x4 px1 = {0.f, 0.f, 0.f, 0.f};   // h0 x-part partial, tile mt1
        {
            bf16x8 bx[4];
            #pragma unroll
            for (int kt = 0; kt < 4; ++kt) bx[kt] = *(const bf16x8*)(xB + kt * 64);
            f32x4 ag0 = bseed[0], ag1 = bseed[1], ag2 = bseed[2], ag3 = bseed[3];
            #pragma unroll
            for (int kt = 0; kt < 4; ++kt) {
                bf16x8 a2 = *(const bf16x8*)(wqA + (((mh * 4 + 2) * 4 + kt) * FB_STRIDE));
                bf16x8 a3 = *(const bf16x8*)(wqA + (((mh * 4 + 3) * 4 + kt) * FB_STRIDE));
                bf16x8 bh = *(const bf16x8*)(hbB + (4 + kt) * 64);   // x-part B frag
                ag0 = __builtin_amdgcn_mfma_f32_16x16x32_bf16(gw0h[kt], bx[kt], ag0, 0, 0, 0);
                ag1 = __builtin_amdgcn_mfma_f32_16x16x32_bf16(gw1h[kt], bx[kt], ag1, 0, 0, 0);
                ag2 = __builtin_amdgcn_mfma_f32_16x16x32_bf16(a2, bx[kt], ag2, 0, 0, 0);
                ag3 = __builtin_amdgcn_mfma_f32_16x16x32_bf16(a3, bx[kt], ag3, 0, 0, 0);
                px0 = __builtin_amdgcn_mfma_f32_16x16x32_bf16(a0w[4 + kt], bh, px0, 0, 0, 0);
                px1 = __builtin_amdgcn_mfma_f32_16x16x32_bf16(a1w[4 + kt], bh, px1, 0, 0, 0);
            }
            char* gw = smem + HB_OFF + e_g * ACT_STRIDE;
            if (row15 == 0) *(uint2*)(gw + (mh * 64 + 0 * 16 + kg * 4) * 2)
                = (uint2){ packbf2(ag0[0], ag0[1]), packbf2(ag0[2], ag0[3]) };
            if (row15 == 1) *(uint2*)(gw + (mh * 64 + 1 * 16 + kg * 4) * 2)
                = (uint2){ packbf2(ag1[0], ag1[1]), packbf2(ag1[2], ag1[3]) };
            if (row15 == 2) *(uint2*)(gw + (mh * 64 + 2 * 16 + kg * 4) * 2)
                = (uint2){ packbf2(ag2[0], ag2[1]), packbf2(ag2[2], ag2[3]) };
            if (row15 == 3) *(uint2*)(gw + (mh * 64 + 3 * 16 + kg * 4) * 2)
                = (uint2){ packbf2(ag3[0], ag3[1]), packbf2(ag3[2], ag3[3]) };
        }
        __syncthreads();   // B1

        // ===== phase B: h0 grad-part (kk=0..3) + combine with px (bit-identical) =====
        {
            f32x4 acc0 = {0.f, 0.f, 0.f, 0.f};
            f32x4 acc1 = {0.f, 0.f, 0.f, 0.f};
            #pragma unroll
            for (int kk = 0; kk < 4; ++kk) {
                bf16x8 bf = *(const bf16x8*)(hbB + kk * 64);
                acc0 = __builtin_amdgcn_mfma_f32_16x16x32_bf16(a0w[kk], bf, acc0, 0, 0, 0);
                acc1 = __builtin_amdgcn_mfma_f32_16x16x32_bf16(a1w[kk], bf, acc1, 0, 0, 0);
            }
            acc0 += px0; acc1 += px1;
            if (cok) {
                uint2 q0 = { packbf2(fmaxf(acc0[0], 0.f), fmaxf(acc0[1], 0.f)),
                             packbf2(fmaxf(acc0[2], 0.f), fmaxf(acc0[3], 0.f)) };
                uint2 q1 = { packbf2(fmaxf(acc1[0], 0.f), fmaxf(acc1[1], 0.f)),
                             packbf2(fmaxf(acc1[2], 0.f), fmaxf(acc1[3], 0.f)) };
                *(uint2*)(smem + H0B_OFF + row15 * ACT_STRIDE + (mt0 * 16 + kg * 4) * 2) = q0;
                *(uint2*)(smem + H0B_OFF + row15 * ACT_STRIDE + (mt1 * 16 + kg * 4) * 2) = q1;
            }
        }
        __syncthreads();   // B2

        PHASE_MLP(h0B, b0w, b1w, H1B_OFF); __syncthreads();   // B3
        PHASE_V(k); __syncthreads();                          // B4
    }
}

extern "C" void kernel_launch(void* const* d_in, const int* in_sizes, int n_in,
                              void* d_out, int out_size, void* d_ws, size_t ws_size,
                              hipStream_t stream)
{
    const float* w  = (const float*)d_in[0];   // [4096,128,128]
    const float* b  = (const float*)d_in[1];   // [4096,128]
    const float* W0 = (const float*)d_in[2];   // [256,256]
    const float* W1 = (const float*)d_in[3];   // [256,256]
    const float* V  = (const float*)d_in[4];   // [128,256]
    float* out = (float*)d_out;                // [4096,128]
    uint16_t* wp = (uint16_t*)d_ws;            // 320 KB packed bf16 weights

    prep_kernel<<<640, 256, 0, stream>>>(W0, W1, V, wp);

    hipFuncSetAttribute((const void*)mlprnn_main,
                        hipFuncAttributeMaxDynamicSharedMemorySize, SMEM_BYTES);
    mlprnn_main<<<NBLOCKS, NTHREADS, SMEM_BYTES, stream>>>(w, b, wp, out);
}

// Round 15
// 178.818 us; speedup vs baseline: 1.1895x; 1.1895x over previous
//
#include <hip/hip_runtime.h>
#include <stdint.h>

#define KSTEPS 20
#define EPB 4          // batch elements per block
#define NBLOCKS 1024   // 4096 / EPB
#define NTHREADS 512

// ---- LDS layout (bytes) ----
// wq : bf16, NEGATED, FRAGMENT-LINEAR with PADDED fb stride:
//      byte(e, fb, slot, h) = e*33792 + fb*1056 + slot*16 + h*8
//      slot = kg_s*16 + r15 (== lane id on the read side), fb = mtile*4 + kt.
//      Reads: base + l*16 + fb*1056 (imm) -> conflict-free, 16B-aligned.
//      Writes: +32B pad per fb -> 16 distinct 8B positions per wave-write.
// hcatB : bf16 [4][272] (cols 0..127 = -grad, 128..255 = x)
// h0B/h1B : bf16 [4][272]
#define WQ_E_STRIDE 33792
#define FB_STRIDE   1056
#define WQ_OFF      0          // 4*33792 = 135168
#define HB_OFF      135168
#define H0B_OFF     137344
#define H1B_OFF     139520
#define SMEM_BYTES  141696

#define ACT_STRIDE 544   // bytes per batch row of bf16 activation buffers

typedef short bf16x8 __attribute__((ext_vector_type(8)));
typedef float f32x4  __attribute__((ext_vector_type(4)));

static __device__ __forceinline__ uint32_t f2bf(float x) {  // RNE round to bf16 (as u16)
    union { float f; uint32_t u; } v; v.f = x;
    return (v.u + 0x7fffu + ((v.u >> 16) & 1u)) >> 16;
}
// v_cvt_pk_bf16_f32: {lo=bf16(a), hi=bf16(b)}, RNE, 1 VALU op per 2 values.
static __device__ __forceinline__ uint32_t packbf2(float a, float b) {
    uint32_t r;
    asm("v_cvt_pk_bf16_f32 %0, %1, %2" : "=v"(r) : "v"(a), "v"(b));
    return r;
}

// Pack shared MLP weights fp32 -> bf16 in layout [c][r][m] : Wp[(c*R + r)*8 + m] = W[r][8c+m]
// == the mfma_f32_16x16x32_bf16 A-fragment layout (lane = row l&15, k-group l>>4).
__global__ void prep_kernel(const float* __restrict__ W0, const float* __restrict__ W1,
                            const float* __restrict__ V, uint16_t* __restrict__ out)
{
    int i = blockIdx.x * 256 + threadIdx.x;   // 640 blocks * 256 = 163840
    float v;
    if (i < 65536) {
        int c = i >> 11, rest = i & 2047, r = rest >> 3, m = rest & 7;
        v = W0[r * 256 + c * 8 + m];
    } else if (i < 131072) {
        int j = i - 65536;
        int c = j >> 11, rest = j & 2047, r = rest >> 3, m = rest & 7;
        v = W1[r * 256 + c * 8 + m];
    } else {
        int j = i - 131072;
        int c = j >> 10, rest = j & 1023, r = rest >> 3, m = rest & 7;
        v = V[r * 256 + c * 8 + m];
    }
    out[i] = (uint16_t)f2bf(v);
}

// Round-14 post-mortem: tripwire fired (WRITE 2MB->22.5MB = spills; 179->213us).
// px0/px1 live across B1 + phase-A transients exceeded the confirmed-full
// 256/wave budget -> weight fragments spilled. REVERTED to the R13 kernel.
// Register wall now triple-bracketed: +32 regs fits (R13), +64 spills (R9),
// +~20 live f32x4 across a barrier spills (R14). Occupancy wall: 135KB wq ->
// 1 block/CU. This structure is at its measured floor (~179us).
__global__
__attribute__((amdgpu_flat_work_group_size(512, 512), amdgpu_waves_per_eu(2, 2)))
void mlprnn_main(
    const float* __restrict__ w, const float* __restrict__ b,
    const uint16_t* __restrict__ wp, float* __restrict__ out)
{
    extern __shared__ char smem[];

    const int t  = threadIdx.x;
    const int e0 = blockIdx.x * EPB;

    // ---- MFMA lane roles ----
    const int l = t & 63, wv = t >> 6;               // wave 0..7
    const int row15 = l & 15;                        // A row within tile / C col
    const int kg    = l >> 4;                        // k-group / C row-group
    const int cm    = l & 3;                         // MLP B source batch
    const bool cok  = row15 < 4;                     // MLP epilogue lanes
    const int mt0 = 2 * wv, mt1 = 2 * wv + 1;        // h0/h1 M-tiles; V tile = wv

    // ---- grad-phase roles: wave -> (element, M-half) ----
    const int e_g  = wv >> 1;                        // element 0..3
    const int mh   = wv & 1;                         // M-half (64 rows)

    const bf16x8* w0v = (const bf16x8*)wp;           // [32][256]
    const bf16x8* w1v = w0v + 32 * 256;
    const bf16x8* vv  = w1v + 32 * 256;              // [32][128]

    // ---- hoist loop-invariant MLP A-fragments into registers ----
    bf16x8 a0w[8], a1w[8], b0w[8], b1w[8], vw[8];
    #pragma unroll
    for (int kk = 0; kk < 8; ++kk) {
        a0w[kk] = w0v[(kk * 4 + kg) * 256 + mt0 * 16 + row15];
        a1w[kk] = w0v[(kk * 4 + kg) * 256 + mt1 * 16 + row15];
        b0w[kk] = w1v[(kk * 4 + kg) * 256 + mt0 * 16 + row15];
        b1w[kk] = w1v[(kk * 4 + kg) * 256 + mt1 * 16 + row15];
        vw[kk]  = vv[(kk * 4 + kg) * 128 + wv * 16 + row15];
    }
    // ---- hoist b for the grad phase: acc seed = b rows (mh*64 + mt*16 + kg*4 ..+4)
    f32x4 bseed[4];
    #pragma unroll
    for (int mt = 0; mt < 4; ++mt)
        bseed[mt] = *(const f32x4*)(b + (size_t)(e0 + e_g) * 128 + mh * 64 + mt * 16 + kg * 4);

    // ---- step 0 shortcut: x=0 -> -grad = b (bit-identical to old k=0 path) ----
    {
        int e = t >> 7, feat = t & 127;
        float bv = b[(size_t)(e0 + e) * 128 + feat];
        *(uint16_t*)(smem + HB_OFF + e * ACT_STRIDE + feat * 2) = (uint16_t)f2bf(bv);
        *(uint16_t*)(smem + HB_OFF + e * ACT_STRIDE + 256 + feat * 2) = 0;  // x = 0
    }
    __syncthreads();

    // ---- staging chunk: 8 iterations of {coalesced f32x4 load, negate+pack, ds_write}
    #define STAGE_CHUNK(C) do {                                                   \
        const float4* wg_ = (const float4*)w;                                     \
        _Pragma("unroll")                                                         \
        for (int it = (C) * 8; it < (C) * 8 + 8; ++it) {                          \
            int g  = it * NTHREADS + t;                                           \
            int e  = g >> 12;                                                     \
            int gg = g & 4095;                                                    \
            int r  = gg >> 5, q = gg & 31;                                        \
            float4 f = wg_[(size_t)(e0 + e) * 4096 + gg];                         \
            uint2 pk = { packbf2(-f.x, -f.y), packbf2(-f.z, -f.w) };              \
            int kt_s = q >> 3, kg_s = (q >> 1) & 3, h = q & 1;                    \
            int fb   = (r >> 4) * 4 + kt_s;                                       \
            int byte = e * WQ_E_STRIDE + fb * FB_STRIDE                           \
                     + (kg_s * 16 + (r & 15)) * 16 + h * 8;                       \
            *(uint2*)(smem + WQ_OFF + byte) = pk;                                 \
        }                                                                         \
    } while (0)

    // grad-phase LDS bases: fragment-linear -> base + l*16 + compile-time fb offset
    const char* wqA = smem + WQ_OFF + e_g * WQ_E_STRIDE + l * 16;
    const char* xB  = smem + HB_OFF + e_g * ACT_STRIDE + 256 + kg * 16;

    // MLP-phase LDS bases
    const char* hbB = smem + HB_OFF  + cm * ACT_STRIDE + kg * 16;
    const char* h0B = smem + H0B_OFF + cm * ACT_STRIDE + kg * 16;
    const char* h1B = smem + H1B_OFF + cm * ACT_STRIDE + kg * 16;

    // gw0h/gw1h (tiles mt 0,1) hoisted after staging completes; declared here.
    bf16x8 gw0h[4], gw1h[4];

    #define PHASE_GRAD() do {                                                     \
        bf16x8 bx[4];                                                             \
        _Pragma("unroll")                                                         \
        for (int kt = 0; kt < 4; ++kt) bx[kt] = *(const bf16x8*)(xB + kt * 64);   \
        f32x4 ag0 = bseed[0], ag1 = bseed[1], ag2 = bseed[2], ag3 = bseed[3];     \
        _Pragma("unroll")                                                         \
        for (int kt = 0; kt < 4; ++kt) {                                          \
            bf16x8 a2 = *(const bf16x8*)(wqA + (((mh * 4 + 2) * 4 + kt) * FB_STRIDE)); \
            bf16x8 a3 = *(const bf16x8*)(wqA + (((mh * 4 + 3) * 4 + kt) * FB_STRIDE)); \
            ag0 = __builtin_amdgcn_mfma_f32_16x16x32_bf16(gw0h[kt], bx[kt], ag0, 0, 0, 0); \
            ag1 = __builtin_amdgcn_mfma_f32_16x16x32_bf16(gw1h[kt], bx[kt], ag1, 0, 0, 0); \
            ag2 = __builtin_amdgcn_mfma_f32_16x16x32_bf16(a2, bx[kt], ag2, 0, 0, 0); \
            ag3 = __builtin_amdgcn_mfma_f32_16x16x32_bf16(a3, bx[kt], ag3, 0, 0, 0); \
        }                                                                         \
        char* gw = smem + HB_OFF + e_g * ACT_STRIDE;                              \
        if (row15 == 0) *(uint2*)(gw + (mh * 64 + 0 * 16 + kg * 4) * 2)           \
            = (uint2){ packbf2(ag0[0], ag0[1]), packbf2(ag0[2], ag0[3]) };        \
        if (row15 == 1) *(uint2*)(gw + (mh * 64 + 1 * 16 + kg * 4) * 2)           \
            = (uint2){ packbf2(ag1[0], ag1[1]), packbf2(ag1[2], ag1[3]) };        \
        if (row15 == 2) *(uint2*)(gw + (mh * 64 + 2 * 16 + kg * 4) * 2)           \
            = (uint2){ packbf2(ag2[0], ag2[1]), packbf2(ag2[2], ag2[3]) };        \
        if (row15 == 3) *(uint2*)(gw + (mh * 64 + 3 * 16 + kg * 4) * 2)           \
            = (uint2){ packbf2(ag3[0], ag3[1]), packbf2(ag3[2], ag3[3]) };        \
    } while (0)

    // 4 chains of 4-deep MFMA: halves serial MFMA latency vs 8-deep.
    #define PHASE_MLP(SRC, AW0, AW1, DST) do {                                    \
        f32x4 acc0 = {0.f, 0.f, 0.f, 0.f}, acc0b = {0.f, 0.f, 0.f, 0.f};          \
        f32x4 acc1 = {0.f, 0.f, 0.f, 0.f}, acc1b = {0.f, 0.f, 0.f, 0.f};          \
        _Pragma("unroll")                                                         \
        for (int kk = 0; kk < 4; ++kk) {                                          \
            bf16x8 bf = *(const bf16x8*)((SRC) + kk * 64);                        \
            acc0 = __builtin_amdgcn_mfma_f32_16x16x32_bf16(AW0[kk], bf, acc0, 0, 0, 0); \
            acc1 = __builtin_amdgcn_mfma_f32_16x16x32_bf16(AW1[kk], bf, acc1, 0, 0, 0); \
        }                                                                         \
        _Pragma("unroll")                                                         \
        for (int kk = 4; kk < 8; ++kk) {                                          \
            bf16x8 bf = *(const bf16x8*)((SRC) + kk * 64);                        \
            acc0b = __builtin_amdgcn_mfma_f32_16x16x32_bf16(AW0[kk], bf, acc0b, 0, 0, 0); \
            acc1b = __builtin_amdgcn_mfma_f32_16x16x32_bf16(AW1[kk], bf, acc1b, 0, 0, 0); \
        }                                                                         \
        acc0 += acc0b; acc1 += acc1b;                                             \
        if (cok) {                                                                \
            uint2 q0 = { packbf2(fmaxf(acc0[0], 0.f), fmaxf(acc0[1], 0.f)),       \
                         packbf2(fmaxf(acc0[2], 0.f), fmaxf(acc0[3], 0.f)) };     \
            uint2 q1 = { packbf2(fmaxf(acc1[0], 0.f), fmaxf(acc1[1], 0.f)),       \
                         packbf2(fmaxf(acc1[2], 0.f), fmaxf(acc1[3], 0.f)) };     \
            *(uint2*)(smem + (DST) + row15 * ACT_STRIDE + (mt0 * 16 + kg * 4) * 2) = q0; \
            *(uint2*)(smem + (DST) + row15 * ACT_STRIDE + (mt1 * 16 + kg * 4) * 2) = q1; \
        }                                                                         \
    } while (0)

    #define PHASE_V(K) do {                                                       \
        f32x4 acc = {0.f, 0.f, 0.f, 0.f}, accb = {0.f, 0.f, 0.f, 0.f};            \
        _Pragma("unroll")                                                         \
        for (int kk = 0; kk < 4; ++kk) {                                          \
            bf16x8 bf = *(const bf16x8*)(h1B + kk * 64);                          \
            acc = __builtin_amdgcn_mfma_f32_16x16x32_bf16(vw[kk], bf, acc, 0, 0, 0); \
        }                                                                         \
        _Pragma("unroll")                                                         \
        for (int kk = 4; kk < 8; ++kk) {                                          \
            bf16x8 bf = *(const bf16x8*)(h1B + kk * 64);                          \
            accb = __builtin_amdgcn_mfma_f32_16x16x32_bf16(vw[kk], bf, accb, 0, 0, 0); \
        }                                                                         \
        acc += accb;                                                              \
        if (cok) {                                                                \
            const int r = wv * 16 + kg * 4;                                       \
            uint2 q = { packbf2(acc[0], acc[1]), packbf2(acc[2], acc[3]) };       \
            *(uint2*)(smem + HB_OFF + row15 * ACT_STRIDE + 256 + r * 2) = q;      \
            if ((K) == KSTEPS - 1) {                                              \
                *(f32x4*)(&out[(size_t)(e0 + row15) * 128 + r]) = acc;            \
            }                                                                     \
        }                                                                         \
    } while (0)

    // ---- step 0 (no grad phase) interleaved with w staging ----
    STAGE_CHUNK(0);
    PHASE_MLP(hbB, a0w, a1w, H0B_OFF); __syncthreads();
    STAGE_CHUNK(1);
    PHASE_MLP(h0B, b0w, b1w, H1B_OFF); __syncthreads();
    STAGE_CHUNK(2);
    PHASE_V(0); __syncthreads();
    STAGE_CHUNK(3);
    __syncthreads();   // wq complete before k=1 grad

    // ---- hoist half the grad A-fragments (tiles mt 0,1; loop-invariant) ----
    #pragma unroll
    for (int kt = 0; kt < 4; ++kt) {
        gw0h[kt] = *(const bf16x8*)(wqA + (((mh * 4 + 0) * 4 + kt) * FB_STRIDE));
        gw1h[kt] = *(const bf16x8*)(wqA + (((mh * 4 + 1) * 4 + kt) * FB_STRIDE));
    }

    // ---- steps 1..19 ----
    #pragma unroll 1
    for (int k = 1; k < KSTEPS; ++k) {
        PHASE_GRAD(); __syncthreads();
        PHASE_MLP(hbB, a0w, a1w, H0B_OFF); __syncthreads();
        PHASE_MLP(h0B, b0w, b1w, H1B_OFF); __syncthreads();
        PHASE_V(k); __syncthreads();
    }
}

extern "C" void kernel_launch(void* const* d_in, const int* in_sizes, int n_in,
                              void* d_out, int out_size, void* d_ws, size_t ws_size,
                              hipStream_t stream)
{
    const float* w  = (const float*)d_in[0];   // [4096,128,128]
    const float* b  = (const float*)d_in[1];   // [4096,128]
    const float* W0 = (const float*)d_in[2];   // [256,256]
    const float* W1 = (const float*)d_in[3];   // [256,256]
    const float* V  = (const float*)d_in[4];   // [128,256]
    float* out = (float*)d_out;                // [4096,128]
    uint16_t* wp = (uint16_t*)d_ws;            // 320 KB packed bf16 weights

    prep_kernel<<<640, 256, 0, stream>>>(W0, W1, V, wp);

    hipFuncSetAttribute((const void*)mlprnn_main,
                        hipFuncAttributeMaxDynamicSharedMemorySize, SMEM_BYTES);
    mlprnn_main<<<NBLOCKS, NTHREADS, SMEM_BYTES, stream>>>(w, b, wp, out);
}